// Round 6
// baseline (332.837 us; speedup 1.0000x reference)
//
#include <hip/hip_runtime.h>

// SVGP-KAN POD moment-matching:
//   mean[b,g] = sum_l a_mu[b,l] * p_mu[g,l]
//   var[b,g]  = sum_l a_var*(p_mu^2 + p_var) + a_mu^2 * p_var
// B=2048, G=16384, L=16. Output = 2 x B x G f32 = 268 MB streaming writes.
// Write-BW-bound: target ~43 us at 6.3 TB/s achievable.

constexpr int L   = 16;   // reduction length (fixed by problem)
constexpr int RG  = 2;    // g-columns per thread -> float2 stores (8B/lane)
constexpr int BT  = 64;   // b-rows per block (amortizes g-side register load)
constexpr int TPB = 256;  // threads per block

typedef float v2f __attribute__((ext_vector_type(2)));

__global__ __launch_bounds__(TPB) void svgp_pod_kernel(
    const float* __restrict__ a_mu, const float* __restrict__ a_var,
    const float* __restrict__ p_mu, const float* __restrict__ p_var,
    float* __restrict__ out_mean, float* __restrict__ out_var,
    int B, int G)
{
    // lane -> RG adjacent g columns; consecutive lanes -> consecutive g pairs
    const int g0 = (blockIdx.x * TPB + threadIdx.x) * RG;
    const int b0 = blockIdx.y * BT;

    // ---- g-side rows resident in registers for the whole b-loop ----
    float pm[RG][L], pv[RG][L], q1[RG][L];
#pragma unroll
    for (int r = 0; r < RG; ++r) {
        const float4* pm4 = reinterpret_cast<const float4*>(p_mu + (long long)(g0 + r) * L);
        const float4* pv4 = reinterpret_cast<const float4*>(p_var + (long long)(g0 + r) * L);
#pragma unroll
        for (int c = 0; c < L / 4; ++c) {
            float4 m = pm4[c], v = pv4[c];
            pm[r][4*c+0] = m.x; pm[r][4*c+1] = m.y; pm[r][4*c+2] = m.z; pm[r][4*c+3] = m.w;
            pv[r][4*c+0] = v.x; pv[r][4*c+1] = v.y; pv[r][4*c+2] = v.z; pv[r][4*c+3] = v.w;
        }
        // q1 = p_mu^2 + p_var, computed once, reused BT times
#pragma unroll
        for (int l = 0; l < L; ++l) q1[r][l] = fmaf(pm[r][l], pm[r][l], pv[r][l]);
    }

    // ---- b-loop: uniform 128B row broadcast-loads (L1-hot), 2x float2 stores ----
    for (int i = 0; i < BT; ++i) {
        const int b = b0 + i;
        const float4* am4 = reinterpret_cast<const float4*>(a_mu + (long long)b * L);
        const float4* av4 = reinterpret_cast<const float4*>(a_var + (long long)b * L);
        float am[L], av[L];
#pragma unroll
        for (int c = 0; c < L / 4; ++c) {
            float4 m = am4[c], v = av4[c];
            am[4*c+0] = m.x; am[4*c+1] = m.y; am[4*c+2] = m.z; am[4*c+3] = m.w;
            av[4*c+0] = v.x; av[4*c+1] = v.y; av[4*c+2] = v.z; av[4*c+3] = v.w;
        }

        float mean[RG] = {0.f, 0.f}, var[RG] = {0.f, 0.f};
#pragma unroll
        for (int l = 0; l < L; ++l) {
            const float am2 = am[l] * am[l];   // shared across the RG g-columns
#pragma unroll
            for (int r = 0; r < RG; ++r) {
                mean[r] = fmaf(am[l], pm[r][l], mean[r]);
                var[r]  = fmaf(av[l], q1[r][l], var[r]);
                var[r]  = fmaf(am2,   pv[r][l], var[r]);
            }
        }

        // 32-bit offset: max b*G+g0 = 2048*16384 = 33.5M << 2^31
        const int off = b * G + g0;
        v2f mo = {mean[0], mean[1]};
        v2f vo = {var[0],  var[1]};
        // outputs are never read again -> nontemporal streaming stores
        __builtin_nontemporal_store(mo, reinterpret_cast<v2f*>(out_mean + off));
        __builtin_nontemporal_store(vo, reinterpret_cast<v2f*>(out_var + off));
    }
}

extern "C" void kernel_launch(void* const* d_in, const int* in_sizes, int n_in,
                              void* d_out, int out_size, void* d_ws, size_t ws_size,
                              hipStream_t stream) {
    const float* a_mu  = (const float*)d_in[0];
    const float* a_var = (const float*)d_in[1];
    const float* p_mu  = (const float*)d_in[2];
    const float* p_var = (const float*)d_in[3];

    const int B = in_sizes[0] / L;      // 2048
    const int G = in_sizes[2] / L;      // 16384

    float* out_mean = (float*)d_out;
    float* out_var  = out_mean + (long long)B * G;

    dim3 grid((unsigned)(G / (TPB * RG)), (unsigned)(B / BT));  // 32 x 32 = 1024 blocks
    svgp_pod_kernel<<<grid, TPB, 0, stream>>>(a_mu, a_var, p_mu, p_var,
                                              out_mean, out_var, B, G);
}

// Round 8
// 324.227 us; speedup vs baseline: 1.0266x; 1.0266x over previous
//
#include <hip/hip_runtime.h>

// SVGP-KAN POD moment-matching:
//   mean[b,g] = sum_l a_mu[b,l] * p_mu[g,l]
//   var[b,g]  = sum_l a_var*(p_mu^2 + p_var) + a_mu^2 * p_var
// B=2048, G=16384, L=16. Output = 2 x B x G f32 = 268 MB streaming writes.
//
// R6 evidence: harness poison fill (plain stores) hits 6.4 TB/s; our kernel
// with __builtin_nontemporal_store managed only ~1.6 TB/s effective.
// R7 single-variable change: NT stores -> plain through-L2 stores.

constexpr int L   = 16;   // reduction length (fixed by problem)
constexpr int RG  = 2;    // g-columns per thread -> float2 stores (8B/lane)
constexpr int BT  = 64;   // b-rows per block (amortizes g-side register load)
constexpr int TPB = 256;  // threads per block

typedef float v2f __attribute__((ext_vector_type(2)));

__global__ __launch_bounds__(TPB) void svgp_pod_kernel(
    const float* __restrict__ a_mu, const float* __restrict__ a_var,
    const float* __restrict__ p_mu, const float* __restrict__ p_var,
    float* __restrict__ out_mean, float* __restrict__ out_var,
    int B, int G)
{
    // lane -> RG adjacent g columns; consecutive lanes -> consecutive g pairs
    const int g0 = (blockIdx.x * TPB + threadIdx.x) * RG;
    const int b0 = blockIdx.y * BT;

    // ---- g-side rows resident in registers for the whole b-loop ----
    float pm[RG][L], pv[RG][L], q1[RG][L];
#pragma unroll
    for (int r = 0; r < RG; ++r) {
        const float4* pm4 = reinterpret_cast<const float4*>(p_mu + (long long)(g0 + r) * L);
        const float4* pv4 = reinterpret_cast<const float4*>(p_var + (long long)(g0 + r) * L);
#pragma unroll
        for (int c = 0; c < L / 4; ++c) {
            float4 m = pm4[c], v = pv4[c];
            pm[r][4*c+0] = m.x; pm[r][4*c+1] = m.y; pm[r][4*c+2] = m.z; pm[r][4*c+3] = m.w;
            pv[r][4*c+0] = v.x; pv[r][4*c+1] = v.y; pv[r][4*c+2] = v.z; pv[r][4*c+3] = v.w;
        }
        // q1 = p_mu^2 + p_var, computed once, reused BT times
#pragma unroll
        for (int l = 0; l < L; ++l) q1[r][l] = fmaf(pm[r][l], pm[r][l], pv[r][l]);
    }

    // ---- b-loop: uniform 128B row broadcast-loads (L1-hot), 2x float2 stores ----
    for (int i = 0; i < BT; ++i) {
        const int b = b0 + i;
        const float4* am4 = reinterpret_cast<const float4*>(a_mu + (long long)b * L);
        const float4* av4 = reinterpret_cast<const float4*>(a_var + (long long)b * L);
        float am[L], av[L];
#pragma unroll
        for (int c = 0; c < L / 4; ++c) {
            float4 m = am4[c], v = av4[c];
            am[4*c+0] = m.x; am[4*c+1] = m.y; am[4*c+2] = m.z; am[4*c+3] = m.w;
            av[4*c+0] = v.x; av[4*c+1] = v.y; av[4*c+2] = v.z; av[4*c+3] = v.w;
        }

        float mean[RG] = {0.f, 0.f}, var[RG] = {0.f, 0.f};
#pragma unroll
        for (int l = 0; l < L; ++l) {
            const float am2 = am[l] * am[l];   // shared across the RG g-columns
#pragma unroll
            for (int r = 0; r < RG; ++r) {
                mean[r] = fmaf(am[l], pm[r][l], mean[r]);
                var[r]  = fmaf(av[l], q1[r][l], var[r]);
                var[r]  = fmaf(am2,   pv[r][l], var[r]);
            }
        }

        // 32-bit offset: max b*G+g0 = 2048*16384 = 33.5M << 2^31
        const int off = b * G + g0;
        v2f mo = {mean[0], mean[1]};
        v2f vo = {var[0],  var[1]};
        // R7: plain through-L2 stores (poison fill proves this path does 6.4 TB/s)
        *reinterpret_cast<v2f*>(out_mean + off) = mo;
        *reinterpret_cast<v2f*>(out_var  + off) = vo;
    }
}

extern "C" void kernel_launch(void* const* d_in, const int* in_sizes, int n_in,
                              void* d_out, int out_size, void* d_ws, size_t ws_size,
                              hipStream_t stream) {
    const float* a_mu  = (const float*)d_in[0];
    const float* a_var = (const float*)d_in[1];
    const float* p_mu  = (const float*)d_in[2];
    const float* p_var = (const float*)d_in[3];

    const int B = in_sizes[0] / L;      // 2048
    const int G = in_sizes[2] / L;      // 16384

    float* out_mean = (float*)d_out;
    float* out_var  = out_mean + (long long)B * G;

    dim3 grid((unsigned)(G / (TPB * RG)), (unsigned)(B / BT));  // 32 x 32 = 1024 blocks
    svgp_pod_kernel<<<grid, TPB, 0, stream>>>(a_mu, a_var, p_mu, p_var,
                                              out_mean, out_var, B, G);
}

// Round 10
// 275.760 us; speedup vs baseline: 1.2070x; 1.1758x over previous
//
#include <hip/hip_runtime.h>

// SVGP-KAN POD moment-matching:
//   mean[b,g] = sum_l a_mu[b,l] * p_mu[g,l]
//   var[b,g]  = sum_l a_var*(p_mu^2 + p_var) + a_mu^2 * p_var
// B=2048, G=16384, L=16. Output = 2 x B x G f32 = 268 MB streaming writes.
//
// R8 post-mortem: NT->plain stores was noise (332->324 us). New theory:
// per-iteration GLOBAL a-row loads share vmcnt with stores; in-order vmcnt
// retire makes each iteration's load-wait also wait for the previous
// iteration's stores to retire -> store-latency serialization (~2 TB/s).
// R9 fix: stage a-rows (+ a_mu^2) in LDS once per block; inner loop reads
// operands via lgkmcnt (ds_read broadcast) so stores are never waited on.
// Math as float2 vector ops to invite v_pk_fma_f32.

constexpr int L   = 16;   // reduction length (fixed by problem)
constexpr int RG  = 2;    // g-columns per thread -> float2 stores (8B/lane)
constexpr int BT  = 64;   // b-rows per block
constexpr int TPB = 256;  // threads per block

typedef float v2f __attribute__((ext_vector_type(2)));

__global__ __launch_bounds__(TPB) void svgp_pod_kernel(
    const float* __restrict__ a_mu, const float* __restrict__ a_var,
    const float* __restrict__ p_mu, const float* __restrict__ p_var,
    float* __restrict__ out_mean, float* __restrict__ out_var,
    int B, int G)
{
    __shared__ float4 s_am [BT][L / 4];   // a_mu rows
    __shared__ float4 s_am2[BT][L / 4];   // a_mu^2 rows (precomputed once)
    __shared__ float4 s_av [BT][L / 4];   // a_var rows

    const int tid = threadIdx.x;
    const int g0  = (blockIdx.x * TPB + tid) * RG;
    const int b0  = blockIdx.y * BT;

    // ---- cooperative a-row staging: 256 thr x 16B = 4KB contiguous per array ----
    {
        const int r = tid >> 2;          // 0..63  (b-row within tile)
        const int c = tid & 3;           // 0..3   (float4 chunk within row)
        const long long base = (long long)(b0 + r) * L + c * 4;
        float4 m = *reinterpret_cast<const float4*>(a_mu + base);
        float4 v = *reinterpret_cast<const float4*>(a_var + base);
        s_am [r][c] = m;
        s_am2[r][c] = make_float4(m.x * m.x, m.y * m.y, m.z * m.z, m.w * m.w);
        s_av [r][c] = v;
    }

    // ---- per-thread g-side fragments: float2 across the RG pair (96 VGPR) ----
    v2f pm2[L], pv2[L], q12[L];
    {
        // rows g0 and g0+1 are contiguous: chunks 0..3 = row g0, 4..7 = row g0+1
        const float4* pm4 = reinterpret_cast<const float4*>(p_mu + (long long)g0 * L);
        const float4* pv4 = reinterpret_cast<const float4*>(p_var + (long long)g0 * L);
        float rmA[L], rmB[L], rvA[L], rvB[L];
#pragma unroll
        for (int c = 0; c < L / 4; ++c) {
            float4 xa = pm4[c], xb = pm4[c + 4];
            float4 ua = pv4[c], ub = pv4[c + 4];
            rmA[4*c+0] = xa.x; rmA[4*c+1] = xa.y; rmA[4*c+2] = xa.z; rmA[4*c+3] = xa.w;
            rmB[4*c+0] = xb.x; rmB[4*c+1] = xb.y; rmB[4*c+2] = xb.z; rmB[4*c+3] = xb.w;
            rvA[4*c+0] = ua.x; rvA[4*c+1] = ua.y; rvA[4*c+2] = ua.z; rvA[4*c+3] = ua.w;
            rvB[4*c+0] = ub.x; rvB[4*c+1] = ub.y; rvB[4*c+2] = ub.z; rvB[4*c+3] = ub.w;
        }
#pragma unroll
        for (int l = 0; l < L; ++l) {
            pm2[l] = (v2f){rmA[l], rmB[l]};
            pv2[l] = (v2f){rvA[l], rvB[l]};
            q12[l] = pm2[l] * pm2[l] + pv2[l];   // contracts to (pk-)fma
        }
    }

    __syncthreads();

    // ---- b-loop: LDS broadcast operands (lgkmcnt), stores never waited on ----
#pragma unroll 2
    for (int i = 0; i < BT; ++i) {
        v2f mean = {0.f, 0.f}, var = {0.f, 0.f};
#pragma unroll
        for (int c = 0; c < L / 4; ++c) {
            const float4 am  = s_am [i][c];
            const float4 am2 = s_am2[i][c];
            const float4 av  = s_av [i][c];
#define POD_STEP(J, AM, AM2, AV)                               \
            {                                                  \
                const int l = 4 * c + (J);                     \
                const v2f amv  = {(AM),  (AM)};                \
                const v2f am2v = {(AM2), (AM2)};               \
                const v2f avv  = {(AV),  (AV)};                \
                mean = amv  * pm2[l] + mean;                   \
                var  = avv  * q12[l] + var;                    \
                var  = am2v * pv2[l] + var;                    \
            }
            POD_STEP(0, am.x, am2.x, av.x)
            POD_STEP(1, am.y, am2.y, av.y)
            POD_STEP(2, am.z, am2.z, av.z)
            POD_STEP(3, am.w, am2.w, av.w)
#undef POD_STEP
        }

        // 32-bit offset: max = 2048*16384 = 33.5M << 2^31
        const int off = (b0 + i) * G + g0;
        *reinterpret_cast<v2f*>(out_mean + off) = mean;
        *reinterpret_cast<v2f*>(out_var  + off) = var;
    }
}

extern "C" void kernel_launch(void* const* d_in, const int* in_sizes, int n_in,
                              void* d_out, int out_size, void* d_ws, size_t ws_size,
                              hipStream_t stream) {
    const float* a_mu  = (const float*)d_in[0];
    const float* a_var = (const float*)d_in[1];
    const float* p_mu  = (const float*)d_in[2];
    const float* p_var = (const float*)d_in[3];

    const int B = in_sizes[0] / L;      // 2048
    const int G = in_sizes[2] / L;      // 16384

    float* out_mean = (float*)d_out;
    float* out_var  = out_mean + (long long)B * G;

    dim3 grid((unsigned)(G / (TPB * RG)), (unsigned)(B / BT));  // 32 x 32 = 1024 blocks
    svgp_pod_kernel<<<grid, TPB, 0, stream>>>(a_mu, a_var, p_mu, p_var,
                                              out_mean, out_var, B, G);
}